// Round 3
// baseline (304.355 us; speedup 1.0000x reference)
//
#include <hip/hip_runtime.h>
#include <math.h>

typedef __bf16 bf16x8 __attribute__((ext_vector_type(8)));
typedef float f32x4 __attribute__((ext_vector_type(4)));
typedef unsigned short ushort8 __attribute__((ext_vector_type(8)));
typedef unsigned short ushort4v __attribute__((ext_vector_type(4)));
typedef unsigned short u16;

#define DEVINL __device__ __forceinline__

DEVINL u16 f2bf(float f) {
    union { float f; unsigned u; } a; a.f = f;
    unsigned u = a.u;
    return (u16)((u + 0x7FFFu + ((u >> 16) & 1u)) >> 16);
}
DEVINL float bf2f(u16 h) { return __uint_as_float(((unsigned)h) << 16); }

DEVINL void gload_lds16(const void* g, void* l) {
    __builtin_amdgcn_global_load_lds(
        (__attribute__((address_space(1))) void*)(g),
        (__attribute__((address_space(3))) void*)(l),
        16, 0, 0);
}

// ---------------------------------------------------------------------------
// 256x256 8-phase GEMM, C = A @ B^T (B stored [N,K] row-major), bf16 in.
// BK=64, 8 waves (2M x 4N), per-wave output 128x64.
// MFMA operands SWAPPED: acc = mfma(bfrag, af, acc) computes C^T in fragment
// space -> lane&15 = C-row, (lane>>4)*4+reg = C-col. Epilogue packs 4
// consecutive cols per fragment into one 8B (bf16) / 16B (f32) store.
// LDS swizzle: byte-col ^= ((row>>1)&3)<<4 (source-side for DMA, read-side).
// XCD-aware bijective block swizzle (all grids have nwg % 8 == 0).
// EPI 0: C(bf16) = acc + bias[col]
// EPI 1: C(bf16) = exp(acc*scale), + fused column-sum partials -> part
// EPI 2: C(f32)  = acc
// ---------------------------------------------------------------------------
template<int EPI>
__global__ __launch_bounds__(512, 2)
void gemm256(const u16* __restrict__ A, int lda, long sAz,
             const u16* __restrict__ B, int ldb, long sBz,
             void* __restrict__ Cv, int ldc, long sCz,
             const float* __restrict__ bias, float* __restrict__ part,
             float scale, int K)
{
    __shared__ u16 lds[65536];   // 128 KiB
    const int tid = threadIdx.x;

    // XCD-aware bijective swizzle of the flattened block id
    const int nx = gridDim.x, ny = gridDim.y;
    const int nwg = nx * ny * gridDim.z;
    const int orig = blockIdx.x + nx * (blockIdx.y + ny * blockIdx.z);
    const int id = (orig & 7) * (nwg >> 3) + (orig >> 3);
    const int tile_x = id % nx;
    const int rem = id / nx;
    const int tile_y = rem % ny;
    const long bz = rem / ny;

    const u16* Ab = A + bz * sAz;
    const u16* Bb = B + bz * sBz;
    const int row0 = tile_x * 256, col0 = tile_y * 256;

    // staging: slab = [256 rows][32 cols] bf16 (64 B rows). row = tid>>2 (+128),
    // byte col = (tid&3)*16 pre-swizzled on the source side; LDS dest linear.
    const int sr = tid >> 2;
    const int csw = ((tid & 3) * 16) ^ (((sr >> 1) & 3) << 4);
    const u16* Ag = Ab + (long)(row0 + sr) * lda + (csw >> 1);
    const u16* Bg = Bb + (long)(col0 + sr) * ldb + (csw >> 1);
    const int dst0 = tid * 8;

    // fragment reads: lane l reads row (+l&15), 16B slot (l>>4), swizzled.
    const int lane = tid & 63, wid = tid >> 6;
    const int wm = wid >> 2, wn = wid & 3;
    const int lane_r = lane & 15;
    const int rdcol = (((lane >> 4) * 16) ^ (((lane_r >> 1) & 3) << 4)) >> 1;
    const int arow0 = wm * 128 + lane_r;
    const int brow0 = wn * 64 + lane_r;

    const int NT = K >> 6;
    f32x4 acc[8][4] = {};
    bf16x8 af[4], bfrag[4];

    auto issueA = [&](int t1, int s, int buf) {
        const u16* g = Ag + (long)t1 * 64 + s * 32;
        u16* d = &lds[(buf * 2 + s) * 8192 + dst0];
        gload_lds16(g, d);
        gload_lds16(g + (long)128 * lda, d + 4096);
    };
    auto issueB = [&](int t1, int s, int buf) {
        const u16* g = Bg + (long)t1 * 64 + s * 32;
        u16* d = &lds[32768 + (buf * 2 + s) * 8192 + dst0];
        gload_lds16(g, d);
        gload_lds16(g + (long)128 * ldb, d + 4096);
    };

#define READ_A(s, h)                                                        \
    _Pragma("unroll")                                                       \
    for (int m = 0; m < 4; ++m)                                             \
        af[m] = *(const bf16x8*)&lds[(buf * 2 + (s)) * 8192 +               \
                     (arow0 + (h) * 64 + m * 16) * 32 + rdcol];

#define READ_B(s)                                                           \
    _Pragma("unroll")                                                       \
    for (int n = 0; n < 4; ++n)                                             \
        bfrag[n] = *(const bf16x8*)&lds[32768 + (buf * 2 + (s)) * 8192 +    \
                     (brow0 + n * 16) * 32 + rdcol];

#define MFMA16(h)                                                           \
    __builtin_amdgcn_s_setprio(1);                                          \
    _Pragma("unroll")                                                       \
    for (int m = 0; m < 4; ++m)                                             \
        _Pragma("unroll")                                                   \
        for (int n = 0; n < 4; ++n)                                         \
            acc[(h) * 4 + m][n] = __builtin_amdgcn_mfma_f32_16x16x32_bf16(  \
                bfrag[n], af[m], acc[(h) * 4 + m][n], 0, 0, 0);             \
    __builtin_amdgcn_s_setprio(0);

    issueA(0, 0, 0); issueB(0, 0, 0); issueA(0, 1, 0); issueB(0, 1, 0);
    asm volatile("s_waitcnt vmcnt(4)" ::: "memory");
    __builtin_amdgcn_s_barrier();

    for (int t = 0; t < NT - 1; ++t) {
        const int buf = t & 1, nbuf = buf ^ 1;
        READ_A(0, 0); READ_B(0);
        issueA(t + 1, 0, nbuf);
        __builtin_amdgcn_s_barrier();
        MFMA16(0);
        __builtin_amdgcn_s_barrier();
        READ_A(0, 1);
        issueB(t + 1, 0, nbuf);
        asm volatile("s_waitcnt vmcnt(4)" ::: "memory");
        __builtin_amdgcn_s_barrier();
        MFMA16(1);
        __builtin_amdgcn_s_barrier();
        READ_A(1, 0); READ_B(1);
        issueA(t + 1, 1, nbuf);
        __builtin_amdgcn_s_barrier();
        MFMA16(0);
        __builtin_amdgcn_s_barrier();
        READ_A(1, 1);
        issueB(t + 1, 1, nbuf);
        asm volatile("s_waitcnt vmcnt(4)" ::: "memory");
        __builtin_amdgcn_s_barrier();
        MFMA16(1);
        __builtin_amdgcn_s_barrier();
    }
    {   // peeled last tile
        const int buf = (NT - 1) & 1;
        READ_A(0, 0); READ_B(0);
        __builtin_amdgcn_s_barrier();
        MFMA16(0);
        __builtin_amdgcn_s_barrier();
        READ_A(0, 1);
        asm volatile("s_waitcnt vmcnt(0)" ::: "memory");
        __builtin_amdgcn_s_barrier();
        MFMA16(1);
        __builtin_amdgcn_s_barrier();
        READ_A(1, 0); READ_B(1);
        __builtin_amdgcn_s_barrier();
        MFMA16(0);
        __builtin_amdgcn_s_barrier();
        READ_A(1, 1);
        __builtin_amdgcn_s_barrier();
        MFMA16(1);
    }
#undef READ_A
#undef READ_B
#undef MFMA16

    // epilogue (swapped layout): row = lane&15, col = (lane>>4)*4 + reg
    const int erow = lane & 15, ecol0 = (lane >> 4) * 4;
    float4 bias4[4];
    if constexpr (EPI == 0) {
#pragma unroll
        for (int nf = 0; nf < 4; ++nf)
            bias4[nf] = *(const float4*)&bias[col0 + wn * 64 + nf * 16 + ecol0];
    }
    f32x4 csum[4] = {};
#pragma unroll
    for (int mf = 0; mf < 8; ++mf) {
        const int gr = row0 + wm * 128 + mf * 16 + erow;
#pragma unroll
        for (int nf = 0; nf < 4; ++nf) {
            const int gc = col0 + wn * 64 + nf * 16 + ecol0;
            f32x4 v = acc[mf][nf];
            if constexpr (EPI == 0) {
                v[0] += bias4[nf].x; v[1] += bias4[nf].y;
                v[2] += bias4[nf].z; v[3] += bias4[nf].w;
                ushort4v o = { f2bf(v[0]), f2bf(v[1]), f2bf(v[2]), f2bf(v[3]) };
                *(ushort4v*)((u16*)Cv + bz * sCz + (long)gr * ldc + gc) = o;
            } else if constexpr (EPI == 1) {
                f32x4 e;
#pragma unroll
                for (int r = 0; r < 4; ++r) e[r] = __expf(v[r] * scale);
                csum[0] += 0.0f;  // keep csum live ordering trivial
                csum[nf] += e;
                ushort4v o = { f2bf(e[0]), f2bf(e[1]), f2bf(e[2]), f2bf(e[3]) };
                *(ushort4v*)((u16*)Cv + bz * sCz + (long)gr * ldc + gc) = o;
            } else {
                *(float4*)((float*)Cv + bz * sCz + (long)gr * ldc + gc) =
                    make_float4(v[0], v[1], v[2], v[3]);
            }
        }
    }
    if constexpr (EPI == 1) {
        // reduce over the 16 lanes of each row-group (they cover 16 rows, same cols)
#pragma unroll
        for (int nf = 0; nf < 4; ++nf)
#pragma unroll
            for (int r = 0; r < 4; ++r) {
                float s = csum[nf][r];
                s += __shfl_xor(s, 1);
                s += __shfl_xor(s, 2);
                s += __shfl_xor(s, 4);
                s += __shfl_xor(s, 8);
                csum[nf][r] = s;
            }
        if ((lane & 15) == 0) {
#pragma unroll
            for (int nf = 0; nf < 4; ++nf) {
                float* p = part + ((bz * 16 + (long)tile_x * 2 + wm) * 2048)
                         + col0 + wn * 64 + nf * 16 + ecol0;
                *(float4*)p = make_float4(csum[nf][0], csum[nf][1],
                                          csum[nf][2], csum[nf][3]);
            }
        }
    }
}

// ---------------------------------------------------------------------------
__global__ void cast_x_k(const float* __restrict__ x, u16* __restrict__ o)
{
    const int i = blockIdx.x * 256 + threadIdx.x;
    const float4* xv = (const float4*)x;
    const float4 a = xv[(long)i * 2], b = xv[(long)i * 2 + 1];
    ushort8 r;
    r[0] = f2bf(a.x); r[1] = f2bf(a.y); r[2] = f2bf(a.z); r[3] = f2bf(a.w);
    r[4] = f2bf(b.x); r[5] = f2bf(b.y); r[6] = f2bf(b.z); r[7] = f2bf(b.w);
    *(ushort8*)(o + (long)i * 8) = r;
}

__global__ void wt_k(const float* __restrict__ Wq, const float* __restrict__ Wk,
                     const float* __restrict__ Wv, u16* __restrict__ Wt)
{
    __shared__ float t[32][33];
    const int z = blockIdx.z;
    const float* W = (z == 0) ? Wq : ((z == 1) ? Wk : Wv);
    const int k0 = blockIdx.x * 32, n0 = blockIdx.y * 32;
    const int tx = threadIdx.x, ty = threadIdx.y;
#pragma unroll
    for (int j = 0; j < 32; j += 8)
        t[ty + j][tx] = W[(long)(k0 + ty + j) * 1024 + n0 + tx];
    __syncthreads();
#pragma unroll
    for (int j = 0; j < 32; j += 8)
        Wt[((long)z * 1024 + n0 + ty + j) * 1024 + k0 + tx] = f2bf(t[tx][ty + j]);
}

__global__ void bias_k(const float* __restrict__ bq, const float* __restrict__ bk,
                       const float* __restrict__ bv, float* __restrict__ bcat)
{
    const int i = blockIdx.x * 256 + threadIdx.x;
    bcat[i] = (i < 1024) ? bq[i] : ((i < 2048) ? bk[i - 1024] : bv[i - 2048]);
}

// rden[b][k] = 1 / sum_c part[b][c][k];  grid (8,8), block 256
__global__ void rcp_k(const float* __restrict__ part, float* __restrict__ rden)
{
    const int b = blockIdx.y;
    const int k = blockIdx.x * 256 + threadIdx.x;
    float s = 0.f;
#pragma unroll
    for (int c = 0; c < 16; ++c) s += part[((long)b * 16 + c) * 2048 + k];
    rden[b * 2048 + k] = 1.0f / s;
}

// Vt[b][d][k] = v[b][k][d] * rden[b][k]; grid (64,32,8), block (32,8)
__global__ void vt_k(const u16* __restrict__ qkv, const float* __restrict__ rden,
                     u16* __restrict__ Vt)
{
    __shared__ float t[32][33];
    const int b = blockIdx.z;
    const int k0 = blockIdx.x * 32, d0 = blockIdx.y * 32;
    const int tx = threadIdx.x, ty = threadIdx.y;
#pragma unroll
    for (int j = 0; j < 32; j += 8) {
        const int k = k0 + ty + j;
        t[ty + j][tx] = bf2f(qkv[((long)b * 2048 + k) * 3072 + 2048 + d0 + tx])
                        * rden[b * 2048 + k];
    }
    __syncthreads();
#pragma unroll
    for (int j = 0; j < 32; j += 8)
        Vt[((long)b * 1024 + d0 + ty + j) * 2048 + k0 + tx] = f2bf(t[tx][ty + j]);
}

// ---------------------------------------------------------------------------
extern "C" void kernel_launch(void* const* d_in, const int* in_sizes, int n_in,
                              void* d_out, int out_size, void* d_ws, size_t ws_size,
                              hipStream_t stream)
{
    const float* x  = (const float*)d_in[0];
    const float* Wq = (const float*)d_in[1];
    const float* bq = (const float*)d_in[2];
    const float* Wk = (const float*)d_in[3];
    const float* bk = (const float*)d_in[4];
    const float* Wv = (const float*)d_in[5];
    const float* bv = (const float*)d_in[6];

    char* ws = (char*)d_ws;
    u16*   qkv  = (u16*)(ws);                     // [16384][3072] bf16
    u16*   E    = (u16*)(ws + 100663296);         // [8][2048][2048] bf16
    u16*   Vt   = (u16*)(ws + 167772160);         // [8][1024][2048] bf16
    u16*   xb   = (u16*)(ws + 201326592);         // [16384][1024] bf16
    u16*   Wt   = (u16*)(ws + 234881024);         // [3072][1024] bf16
    float* bcat = (float*)(ws + 241172480);       // [3072] f32
    float* part = (float*)(ws + 241184768);       // [8][16][2048] f32
    float* rden = (float*)(ws + 243281920);       // [8][2048] f32

    const long sQKV = (long)2048 * 3072;
    const long sE   = (long)2048 * 2048;
    const long sVt  = (long)1024 * 2048;
    const long sO   = (long)2048 * 1024;

    cast_x_k<<<8192, 256, 0, stream>>>(x, xb);
    wt_k<<<dim3(32, 32, 3), dim3(32, 8), 0, stream>>>(Wq, Wk, Wv, Wt);
    bias_k<<<12, 256, 0, stream>>>(bq, bk, bv, bcat);
    // qkv = x @ Wt^T + bias   (M=16384, N=3072, K=1024)
    gemm256<0><<<dim3(64, 12, 1), 512, 0, stream>>>(
        xb, 1024, 0, Wt, 1024, 0, qkv, 3072, 0, bcat, nullptr, 0.f, 1024);
    // E = exp(scale * Q @ K^T), fused column-sum partials (M=N=2048, K=1024)
    gemm256<1><<<dim3(8, 8, 8), 512, 0, stream>>>(
        qkv, 3072, sQKV, qkv + 1024, 3072, sQKV, E, 2048, sE,
        nullptr, part, 0.03125f, 1024);
    rcp_k<<<dim3(8, 8), 256, 0, stream>>>(part, rden);
    vt_k<<<dim3(64, 32, 8), dim3(32, 8), 0, stream>>>(qkv, rden, Vt);
    // out = E @ Vt^T  (M=2048, N=1024, K=2048, fp32 out)
    gemm256<2><<<dim3(8, 4, 8), 512, 0, stream>>>(
        E, 2048, sE, Vt, 2048, sVt, d_out, 1024, sO,
        nullptr, nullptr, 1.f, 2048);
}

// Round 4
// 303.688 us; speedup vs baseline: 1.0022x; 1.0022x over previous
//
#include <hip/hip_runtime.h>
#include <math.h>

typedef __bf16 bf16x8 __attribute__((ext_vector_type(8)));
typedef float f32x4 __attribute__((ext_vector_type(4)));
typedef unsigned short ushort8 __attribute__((ext_vector_type(8)));
typedef unsigned short ushort4v __attribute__((ext_vector_type(4)));
typedef unsigned short u16;

#define DEVINL __device__ __forceinline__

DEVINL u16 f2bf(float f) {
    union { float f; unsigned u; } a; a.f = f;
    unsigned u = a.u;
    return (u16)((u + 0x7FFFu + ((u >> 16) & 1u)) >> 16);
}
DEVINL float bf2f(u16 h) { return __uint_as_float(((unsigned)h) << 16); }

DEVINL void gload_lds16(const void* g, void* l) {
    __builtin_amdgcn_global_load_lds(
        (__attribute__((address_space(1))) void*)(g),
        (__attribute__((address_space(3))) void*)(l),
        16, 0, 0);
}

// ---------------------------------------------------------------------------
// 256x256 GEMM, C = A @ B^T (B stored [N,K] row-major), bf16 in.
// BK=64, 8 waves (2M x 4N), per-wave output 128x64.
// Swapped MFMA operands: acc = mfma(bfrag, af) computes C^T fragments ->
// lane&15 = C-row, (lane>>4)*4+reg = C-col -> packed 8B/16B stores.
// Relaxed sync: 2 barriers per K-tile, each right after a counted vmcnt(4)
// gate ("memory" clobber orders the surrounding LDS reads). Waves drift
// between gates so ds_read and MFMA overlap across waves.
// Buffer-race proof: reads of slab s(t) happen after the vmcnt+barrier pair
// that confirmed its DMA; the last ds_read of a region is consumed by an
// MFMA (lgkmcnt) before that wave reaches the next barrier, and DMA reissue
// into the region happens only after that barrier releases.
// EPI 0: C(bf16)=acc+bias[col]; EPI 1: C(bf16)=exp(acc*scale) + colsum->part;
// EPI 2: C(f32)=acc
// ---------------------------------------------------------------------------
template<int EPI>
__global__ __launch_bounds__(512, 2)
void gemm256(const u16* __restrict__ A, int lda, long sAz,
             const u16* __restrict__ B, int ldb, long sBz,
             void* __restrict__ Cv, int ldc, long sCz,
             const float* __restrict__ bias, float* __restrict__ part,
             float scale, int K)
{
    __shared__ u16 lds[65536];   // 128 KiB
    const int tid = threadIdx.x;
    const int tile_x = blockIdx.x, tile_y = blockIdx.y;
    const long bz = blockIdx.z;

    const u16* Ab = A + bz * sAz;
    const u16* Bb = B + bz * sBz;
    const int row0 = tile_x * 256, col0 = tile_y * 256;

    // staging: slab = [256 rows][32 cols] bf16 (64 B rows). row = tid>>2 (+128),
    // byte col = (tid&3)*16 pre-swizzled on the source side; LDS dest linear.
    const int sr = tid >> 2;
    const int csw = ((tid & 3) * 16) ^ (((sr >> 1) & 3) << 4);
    const u16* Ag = Ab + (long)(row0 + sr) * lda + (csw >> 1);
    const u16* Bg = Bb + (long)(col0 + sr) * ldb + (csw >> 1);
    const int dst0 = tid * 8;

    // fragment reads: lane l reads row (+l&15), 16B slot (l>>4), swizzled.
    const int lane = tid & 63, wid = tid >> 6;
    const int wm = wid >> 2, wn = wid & 3;
    const int lane_r = lane & 15;
    const int rdcol = (((lane >> 4) * 16) ^ (((lane_r >> 1) & 3) << 4)) >> 1;
    const int arow0 = wm * 128 + lane_r;
    const int brow0 = wn * 64 + lane_r;

    const int NT = K >> 6;
    f32x4 acc[8][4] = {};
    bf16x8 af[4], bfrag[4];

    auto issueA = [&](int t1, int s, int buf) {
        const u16* g = Ag + (long)t1 * 64 + s * 32;
        u16* d = &lds[(buf * 2 + s) * 8192 + dst0];
        gload_lds16(g, d);
        gload_lds16(g + (long)128 * lda, d + 4096);
    };
    auto issueB = [&](int t1, int s, int buf) {
        const u16* g = Bg + (long)t1 * 64 + s * 32;
        u16* d = &lds[32768 + (buf * 2 + s) * 8192 + dst0];
        gload_lds16(g, d);
        gload_lds16(g + (long)128 * ldb, d + 4096);
    };

#define READ_A(s, h)                                                        \
    _Pragma("unroll")                                                       \
    for (int m = 0; m < 4; ++m)                                             \
        af[m] = *(const bf16x8*)&lds[(buf * 2 + (s)) * 8192 +               \
                     (arow0 + (h) * 64 + m * 16) * 32 + rdcol];

#define READ_B(s)                                                           \
    _Pragma("unroll")                                                       \
    for (int n = 0; n < 4; ++n)                                             \
        bfrag[n] = *(const bf16x8*)&lds[32768 + (buf * 2 + (s)) * 8192 +    \
                     (brow0 + n * 16) * 32 + rdcol];

#define MFMA16(h)                                                           \
    __builtin_amdgcn_s_setprio(1);                                          \
    _Pragma("unroll")                                                       \
    for (int m = 0; m < 4; ++m)                                             \
        _Pragma("unroll")                                                   \
        for (int n = 0; n < 4; ++n)                                         \
            acc[(h) * 4 + m][n] = __builtin_amdgcn_mfma_f32_16x16x32_bf16(  \
                bfrag[n], af[m], acc[(h) * 4 + m][n], 0, 0, 0);             \
    __builtin_amdgcn_s_setprio(0);

#define GATE(n)                                                             \
    asm volatile("s_waitcnt vmcnt(" #n ")" ::: "memory");                   \
    __builtin_amdgcn_s_barrier();

    issueA(0, 0, 0); issueB(0, 0, 0); issueA(0, 1, 0); issueB(0, 1, 0);
    GATE(4);

    for (int t = 0; t < NT - 1; ++t) {
        const int buf = t & 1, nbuf = buf ^ 1;
        // half-tile s0 (two MFMA quadrants), prefetch A_s0/B_s0 of t+1
        READ_A(0, 0); READ_B(0);
        issueA(t + 1, 0, nbuf);
        MFMA16(0);
        READ_A(0, 1);
        issueB(t + 1, 0, nbuf);
        MFMA16(1);
        GATE(4);   // s1(t) landed (collectively)
        // half-tile s1, prefetch A_s1/B_s1 of t+1
        READ_A(1, 0); READ_B(1);
        issueA(t + 1, 1, nbuf);
        MFMA16(0);
        READ_A(1, 1);
        issueB(t + 1, 1, nbuf);
        MFMA16(1);
        GATE(4);   // s0(t+1) landed
    }
    {   // peeled last tile: no prefetch
        const int buf = (NT - 1) & 1;
        READ_A(0, 0); READ_B(0);
        MFMA16(0);
        READ_A(0, 1);
        MFMA16(1);
        GATE(0);   // s1(last) landed
        READ_A(1, 0); READ_B(1);
        MFMA16(0);
        READ_A(1, 1);
        MFMA16(1);
    }
#undef READ_A
#undef READ_B
#undef MFMA16
#undef GATE

    // epilogue (swapped layout): row = lane&15, col = (lane>>4)*4 + reg
    const int erow = lane & 15, ecol0 = (lane >> 4) * 4;
    float4 bias4[4];
    if constexpr (EPI == 0) {
#pragma unroll
        for (int nf = 0; nf < 4; ++nf)
            bias4[nf] = *(const float4*)&bias[col0 + wn * 64 + nf * 16 + ecol0];
    }
    f32x4 csum[4] = {};
#pragma unroll
    for (int mf = 0; mf < 8; ++mf) {
        const int gr = row0 + wm * 128 + mf * 16 + erow;
#pragma unroll
        for (int nf = 0; nf < 4; ++nf) {
            const int gc = col0 + wn * 64 + nf * 16 + ecol0;
            f32x4 v = acc[mf][nf];
            if constexpr (EPI == 0) {
                v[0] += bias4[nf].x; v[1] += bias4[nf].y;
                v[2] += bias4[nf].z; v[3] += bias4[nf].w;
                ushort4v o = { f2bf(v[0]), f2bf(v[1]), f2bf(v[2]), f2bf(v[3]) };
                *(ushort4v*)((u16*)Cv + bz * sCz + (long)gr * ldc + gc) = o;
            } else if constexpr (EPI == 1) {
                f32x4 e;
#pragma unroll
                for (int r = 0; r < 4; ++r) e[r] = __expf(v[r] * scale);
                csum[nf] += e;
                ushort4v o = { f2bf(e[0]), f2bf(e[1]), f2bf(e[2]), f2bf(e[3]) };
                *(ushort4v*)((u16*)Cv + bz * sCz + (long)gr * ldc + gc) = o;
            } else {
                *(float4*)((float*)Cv + bz * sCz + (long)gr * ldc + gc) =
                    make_float4(v[0], v[1], v[2], v[3]);
            }
        }
    }
    if constexpr (EPI == 1) {
#pragma unroll
        for (int nf = 0; nf < 4; ++nf)
#pragma unroll
            for (int r = 0; r < 4; ++r) {
                float s = csum[nf][r];
                s += __shfl_xor(s, 1);
                s += __shfl_xor(s, 2);
                s += __shfl_xor(s, 4);
                s += __shfl_xor(s, 8);
                csum[nf][r] = s;
            }
        if ((lane & 15) == 0) {
#pragma unroll
            for (int nf = 0; nf < 4; ++nf) {
                float* p = part + ((bz * 16 + (long)tile_x * 2 + wm) * 2048)
                         + col0 + wn * 64 + nf * 16 + ecol0;
                *(float4*)p = make_float4(csum[nf][0], csum[nf][1],
                                          csum[nf][2], csum[nf][3]);
            }
        }
    }
}

// ---------------------------------------------------------------------------
__global__ void cast_x_k(const float* __restrict__ x, u16* __restrict__ o)
{
    const int i = blockIdx.x * 256 + threadIdx.x;
    const float4* xv = (const float4*)x;
    const float4 a = xv[(long)i * 2], b = xv[(long)i * 2 + 1];
    ushort8 r;
    r[0] = f2bf(a.x); r[1] = f2bf(a.y); r[2] = f2bf(a.z); r[3] = f2bf(a.w);
    r[4] = f2bf(b.x); r[5] = f2bf(b.y); r[6] = f2bf(b.z); r[7] = f2bf(b.w);
    *(ushort8*)(o + (long)i * 8) = r;
}

__global__ void wt_k(const float* __restrict__ Wq, const float* __restrict__ Wk,
                     const float* __restrict__ Wv, u16* __restrict__ Wt)
{
    __shared__ float t[32][33];
    const int z = blockIdx.z;
    const float* W = (z == 0) ? Wq : ((z == 1) ? Wk : Wv);
    const int k0 = blockIdx.x * 32, n0 = blockIdx.y * 32;
    const int tx = threadIdx.x, ty = threadIdx.y;
#pragma unroll
    for (int j = 0; j < 32; j += 8)
        t[ty + j][tx] = W[(long)(k0 + ty + j) * 1024 + n0 + tx];
    __syncthreads();
#pragma unroll
    for (int j = 0; j < 32; j += 8)
        Wt[((long)z * 1024 + n0 + ty + j) * 1024 + k0 + tx] = f2bf(t[tx][ty + j]);
}

__global__ void bias_k(const float* __restrict__ bq, const float* __restrict__ bk,
                       const float* __restrict__ bv, float* __restrict__ bcat)
{
    const int i = blockIdx.x * 256 + threadIdx.x;
    bcat[i] = (i < 1024) ? bq[i] : ((i < 2048) ? bk[i - 1024] : bv[i - 2048]);
}

// rden[b][k] = 1 / sum_c part[b][c][k];  grid (8,8), block 256
__global__ void rcp_k(const float* __restrict__ part, float* __restrict__ rden)
{
    const int b = blockIdx.y;
    const int k = blockIdx.x * 256 + threadIdx.x;
    float s = 0.f;
#pragma unroll
    for (int c = 0; c < 16; ++c) s += part[((long)b * 16 + c) * 2048 + k];
    rden[b * 2048 + k] = 1.0f / s;
}

// Vt[b][d][k] = v[b][k][d] * rden[b][k]; grid (64,32,8), block (32,8)
__global__ void vt_k(const u16* __restrict__ qkv, const float* __restrict__ rden,
                     u16* __restrict__ Vt)
{
    __shared__ float t[32][33];
    const int b = blockIdx.z;
    const int k0 = blockIdx.x * 32, d0 = blockIdx.y * 32;
    const int tx = threadIdx.x, ty = threadIdx.y;
#pragma unroll
    for (int j = 0; j < 32; j += 8) {
        const int k = k0 + ty + j;
        t[ty + j][tx] = bf2f(qkv[((long)b * 2048 + k) * 3072 + 2048 + d0 + tx])
                        * rden[b * 2048 + k];
    }
    __syncthreads();
#pragma unroll
    for (int j = 0; j < 32; j += 8)
        Vt[((long)b * 1024 + d0 + ty + j) * 2048 + k0 + tx] = f2bf(t[tx][ty + j]);
}

// ---------------------------------------------------------------------------
extern "C" void kernel_launch(void* const* d_in, const int* in_sizes, int n_in,
                              void* d_out, int out_size, void* d_ws, size_t ws_size,
                              hipStream_t stream)
{
    const float* x  = (const float*)d_in[0];
    const float* Wq = (const float*)d_in[1];
    const float* bq = (const float*)d_in[2];
    const float* Wk = (const float*)d_in[3];
    const float* bk = (const float*)d_in[4];
    const float* Wv = (const float*)d_in[5];
    const float* bv = (const float*)d_in[6];

    char* ws = (char*)d_ws;
    u16*   qkv  = (u16*)(ws);                     // [16384][3072] bf16
    u16*   E    = (u16*)(ws + 100663296);         // [8][2048][2048] bf16
    u16*   Vt   = (u16*)(ws + 167772160);         // [8][1024][2048] bf16
    u16*   xb   = (u16*)(ws + 201326592);         // [16384][1024] bf16
    u16*   Wt   = (u16*)(ws + 234881024);         // [3072][1024] bf16
    float* bcat = (float*)(ws + 241172480);       // [3072] f32
    float* part = (float*)(ws + 241184768);       // [8][16][2048] f32
    float* rden = (float*)(ws + 243281920);       // [8][2048] f32

    const long sQKV = (long)2048 * 3072;
    const long sE   = (long)2048 * 2048;
    const long sVt  = (long)1024 * 2048;
    const long sO   = (long)2048 * 1024;

    cast_x_k<<<8192, 256, 0, stream>>>(x, xb);
    wt_k<<<dim3(32, 32, 3), dim3(32, 8), 0, stream>>>(Wq, Wk, Wv, Wt);
    bias_k<<<12, 256, 0, stream>>>(bq, bk, bv, bcat);
    // qkv = x @ Wt^T + bias   (M=16384, N=3072, K=1024)
    gemm256<0><<<dim3(64, 12, 1), 512, 0, stream>>>(
        xb, 1024, 0, Wt, 1024, 0, qkv, 3072, 0, bcat, nullptr, 0.f, 1024);
    // E = exp(scale * Q @ K^T), fused column-sum partials (M=N=2048, K=1024)
    gemm256<1><<<dim3(8, 8, 8), 512, 0, stream>>>(
        qkv, 3072, sQKV, qkv + 1024, 3072, sQKV, E, 2048, sE,
        nullptr, part, 0.03125f, 1024);
    rcp_k<<<dim3(8, 8), 256, 0, stream>>>(part, rden);
    vt_k<<<dim3(64, 32, 8), dim3(32, 8), 0, stream>>>(qkv, rden, Vt);
    // out = E @ Vt^T  (M=2048, N=1024, K=2048, fp32 out)
    gemm256<2><<<dim3(8, 4, 8), 512, 0, stream>>>(
        E, 2048, sE, Vt, 2048, sVt, d_out, 1024, sO,
        nullptr, nullptr, 1.f, 2048);
}

// Round 5
// 300.970 us; speedup vs baseline: 1.0112x; 1.0090x over previous
//
#include <hip/hip_runtime.h>
#include <math.h>

typedef __bf16 bf16x8 __attribute__((ext_vector_type(8)));
typedef float f32x4 __attribute__((ext_vector_type(4)));
typedef unsigned short ushort8 __attribute__((ext_vector_type(8)));
typedef unsigned short ushort4v __attribute__((ext_vector_type(4)));
typedef unsigned short u16;

#define DEVINL __device__ __forceinline__

DEVINL u16 f2bf(float f) {
    union { float f; unsigned u; } a; a.f = f;
    unsigned u = a.u;
    return (u16)((u + 0x7FFFu + ((u >> 16) & 1u)) >> 16);
}
DEVINL float bf2f(u16 h) { return __uint_as_float(((unsigned)h) << 16); }

DEVINL void gload_lds16(const void* g, void* l) {
    __builtin_amdgcn_global_load_lds(
        (__attribute__((address_space(1))) void*)(g),
        (__attribute__((address_space(3))) void*)(l),
        16, 0, 0);
}

// ---------------------------------------------------------------------------
// 256x256 GEMM, C = A @ B^T (B stored [N,K] row-major), bf16 in.
// BK=64 (2 slabs of 32), 8 waves (2M x 4N), per-wave output 128x64.
// WITHIN-WAVE SW PIPELINE: two fragment register sets; phase p issues
// ds_reads for phase p+1 into the idle set while MFMAs consume the ready set
// -> MFMA never waits on same-phase lgkmcnt; LDS and MFMA pipes overlap
// inside each wave (needed: 128KiB LDS -> 1 block/CU -> only 2 waves/SIMD).
// Sync: 2 gates per K-tile (counted vmcnt(4) + barrier). Staging of K-tile
// t+1 slabs at phases 1 and 3 of tile t. Race-freedom: every slab read is
// covered by the gate that confirmed its DMA; last ds_read of a region
// completes (lgkmcnt before consuming MFMA) >=1 barrier before any DMA
// reissue into that region.
// Swapped MFMA operands -> C^T fragment layout -> packed 8B/16B stores.
// EPI 0: C(bf16)=acc+bias[col]; EPI 1: C(bf16)=exp(acc*scale)+colsum->part;
// EPI 2: C(f32)=acc
// ---------------------------------------------------------------------------
template<int EPI>
__global__ __launch_bounds__(512, 2)
void gemm256(const u16* __restrict__ A, int lda, long sAz,
             const u16* __restrict__ B, int ldb, long sBz,
             void* __restrict__ Cv, int ldc, long sCz,
             const float* __restrict__ bias, float* __restrict__ part,
             float scale, int K)
{
    __shared__ u16 lds[65536];   // 128 KiB
    const int tid = threadIdx.x;
    const int tile_x = blockIdx.x, tile_y = blockIdx.y;
    const long bz = blockIdx.z;

    const u16* Ab = A + bz * sAz;
    const u16* Bb = B + bz * sBz;
    const int row0 = tile_x * 256, col0 = tile_y * 256;

    // staging: slab = [256 rows][32 cols] bf16 (64 B rows). row = tid>>2 (+128),
    // byte col = (tid&3)*16 pre-swizzled on the source side; LDS dest linear.
    const int sr = tid >> 2;
    const int csw = ((tid & 3) * 16) ^ (((sr >> 1) & 3) << 4);
    const u16* Ag = Ab + (long)(row0 + sr) * lda + (csw >> 1);
    const u16* Bg = Bb + (long)(col0 + sr) * ldb + (csw >> 1);
    const int dst0 = tid * 8;

    // fragment reads: lane reads row (+lane&15), 16B slot (lane>>4), swizzled.
    const int lane = tid & 63, wid = tid >> 6;
    const int wm = wid >> 2, wn = wid & 3;
    const int lane_r = lane & 15;
    const int rdcol = (((lane >> 4) * 16) ^ (((lane_r >> 1) & 3) << 4)) >> 1;
    const int arow0 = wm * 128 + lane_r;
    const int brow0 = wn * 64 + lane_r;

    const int NT = K >> 6;
    f32x4 acc[8][4] = {};
    bf16x8 aF0[4], bF0[4], aF1[4], bF1[4];

    auto issueA = [&](int t1, int s, int b) {
        const u16* g = Ag + (long)t1 * 64 + s * 32;
        u16* d = &lds[(b * 2 + s) * 8192 + dst0];
        gload_lds16(g, d);
        gload_lds16(g + (long)128 * lda, d + 4096);
    };
    auto issueB = [&](int t1, int s, int b) {
        const u16* g = Bg + (long)t1 * 64 + s * 32;
        u16* d = &lds[32768 + (b * 2 + s) * 8192 + dst0];
        gload_lds16(g, d);
        gload_lds16(g + (long)128 * ldb, d + 4096);
    };

#define READ_AB(bufv, s, h, SET)                                            \
    _Pragma("unroll")                                                       \
    for (int m = 0; m < 4; ++m)                                             \
        aF##SET[m] = *(const bf16x8*)&lds[((bufv) * 2 + (s)) * 8192 +       \
                         (arow0 + (h) * 64 + m * 16) * 32 + rdcol];         \
    _Pragma("unroll")                                                       \
    for (int n = 0; n < 4; ++n)                                             \
        bF##SET[n] = *(const bf16x8*)&lds[32768 + ((bufv) * 2 + (s)) * 8192 \
                         + (brow0 + n * 16) * 32 + rdcol];

#define MFMA16S(SET, h)                                                     \
    __builtin_amdgcn_s_setprio(1);                                          \
    _Pragma("unroll")                                                       \
    for (int m = 0; m < 4; ++m)                                             \
        _Pragma("unroll")                                                   \
        for (int n = 0; n < 4; ++n)                                         \
            acc[(h) * 4 + m][n] = __builtin_amdgcn_mfma_f32_16x16x32_bf16(  \
                bF##SET[n], aF##SET[m], acc[(h) * 4 + m][n], 0, 0, 0);      \
    __builtin_amdgcn_s_setprio(0);

#define GATE(n)                                                             \
    asm volatile("s_waitcnt vmcnt(" #n ")" ::: "memory");                   \
    __builtin_amdgcn_s_barrier();

    // prologue: K-tile 0 both slabs -> buf0; confirm s0
    issueA(0, 0, 0); issueB(0, 0, 0);
    issueA(0, 1, 0); issueB(0, 1, 0);
    GATE(4);
    READ_AB(0, 0, 0, 0);   // (s0,h0) -> set0

    for (int t = 0; t < NT - 1; ++t) {
        const int buf = t & 1, nbuf = buf ^ 1;
        // P1: stage s0(t+1); read (s0,h1)->set1; MFMA set0
        issueA(t + 1, 0, nbuf); issueB(t + 1, 0, nbuf);
        READ_AB(buf, 0, 1, 1);
        MFMA16S(0, 0);
        GATE(4);              // confirms s1(t)
        // P2: read (s1,h0)->set0; MFMA set1
        READ_AB(buf, 1, 0, 0);
        MFMA16S(1, 1);
        // P3: stage s1(t+1); read (s1,h1)->set1; MFMA set0
        issueA(t + 1, 1, nbuf); issueB(t + 1, 1, nbuf);
        READ_AB(buf, 1, 1, 1);
        MFMA16S(0, 0);
        GATE(4);              // confirms s0(t+1)
        // P4: read (s0(t+1),h0)->set0; MFMA set1
        READ_AB(nbuf, 0, 0, 0);
        MFMA16S(1, 1);
    }
    {   // peeled last K-tile (no staging)
        const int buf = (NT - 1) & 1;
        READ_AB(buf, 0, 1, 1);
        MFMA16S(0, 0);
        GATE(0);              // confirms s1(last)
        READ_AB(buf, 1, 0, 0);
        MFMA16S(1, 1);
        READ_AB(buf, 1, 1, 1);
        MFMA16S(0, 0);
        MFMA16S(1, 1);
    }
#undef READ_AB
#undef MFMA16S
#undef GATE

    // epilogue (swapped layout): row = lane&15, col = (lane>>4)*4 + reg
    const int erow = lane & 15, ecol0 = (lane >> 4) * 4;
    float4 bias4[4];
    if constexpr (EPI == 0) {
#pragma unroll
        for (int nf = 0; nf < 4; ++nf)
            bias4[nf] = *(const float4*)&bias[col0 + wn * 64 + nf * 16 + ecol0];
    }
    f32x4 csum[4] = {};
#pragma unroll
    for (int mf = 0; mf < 8; ++mf) {
        const int gr = row0 + wm * 128 + mf * 16 + erow;
#pragma unroll
        for (int nf = 0; nf < 4; ++nf) {
            const int gc = col0 + wn * 64 + nf * 16 + ecol0;
            f32x4 v = acc[mf][nf];
            if constexpr (EPI == 0) {
                v[0] += bias4[nf].x; v[1] += bias4[nf].y;
                v[2] += bias4[nf].z; v[3] += bias4[nf].w;
                ushort4v o = { f2bf(v[0]), f2bf(v[1]), f2bf(v[2]), f2bf(v[3]) };
                *(ushort4v*)((u16*)Cv + bz * sCz + (long)gr * ldc + gc) = o;
            } else if constexpr (EPI == 1) {
                f32x4 e;
#pragma unroll
                for (int r = 0; r < 4; ++r) e[r] = __expf(v[r] * scale);
                csum[nf] += e;
                ushort4v o = { f2bf(e[0]), f2bf(e[1]), f2bf(e[2]), f2bf(e[3]) };
                *(ushort4v*)((u16*)Cv + bz * sCz + (long)gr * ldc + gc) = o;
            } else {
                *(float4*)((float*)Cv + bz * sCz + (long)gr * ldc + gc) =
                    make_float4(v[0], v[1], v[2], v[3]);
            }
        }
    }
    if constexpr (EPI == 1) {
#pragma unroll
        for (int nf = 0; nf < 4; ++nf)
#pragma unroll
            for (int r = 0; r < 4; ++r) {
                float s = csum[nf][r];
                s += __shfl_xor(s, 1);
                s += __shfl_xor(s, 2);
                s += __shfl_xor(s, 4);
                s += __shfl_xor(s, 8);
                csum[nf][r] = s;
            }
        if ((lane & 15) == 0) {
#pragma unroll
            for (int nf = 0; nf < 4; ++nf) {
                float* p = part + ((bz * 16 + (long)tile_x * 2 + wm) * 2048)
                         + col0 + wn * 64 + nf * 16 + ecol0;
                *(float4*)p = make_float4(csum[nf][0], csum[nf][1],
                                          csum[nf][2], csum[nf][3]);
            }
        }
    }
}

// ---------------------------------------------------------------------------
__global__ void cast_x_k(const float* __restrict__ x, u16* __restrict__ o)
{
    const int i = blockIdx.x * 256 + threadIdx.x;
    const float4* xv = (const float4*)x;
    const float4 a = xv[(long)i * 2], b = xv[(long)i * 2 + 1];
    ushort8 r;
    r[0] = f2bf(a.x); r[1] = f2bf(a.y); r[2] = f2bf(a.z); r[3] = f2bf(a.w);
    r[4] = f2bf(b.x); r[5] = f2bf(b.y); r[6] = f2bf(b.z); r[7] = f2bf(b.w);
    *(ushort8*)(o + (long)i * 8) = r;
}

__global__ void wt_k(const float* __restrict__ Wq, const float* __restrict__ Wk,
                     const float* __restrict__ Wv, u16* __restrict__ Wt)
{
    __shared__ float t[32][33];
    const int z = blockIdx.z;
    const float* W = (z == 0) ? Wq : ((z == 1) ? Wk : Wv);
    const int k0 = blockIdx.x * 32, n0 = blockIdx.y * 32;
    const int tx = threadIdx.x, ty = threadIdx.y;
#pragma unroll
    for (int j = 0; j < 32; j += 8)
        t[ty + j][tx] = W[(long)(k0 + ty + j) * 1024 + n0 + tx];
    __syncthreads();
#pragma unroll
    for (int j = 0; j < 32; j += 8)
        Wt[((long)z * 1024 + n0 + ty + j) * 1024 + k0 + tx] = f2bf(t[tx][ty + j]);
}

__global__ void bias_k(const float* __restrict__ bq, const float* __restrict__ bk,
                       const float* __restrict__ bv, float* __restrict__ bcat)
{
    const int i = blockIdx.x * 256 + threadIdx.x;
    bcat[i] = (i < 1024) ? bq[i] : ((i < 2048) ? bk[i - 1024] : bv[i - 2048]);
}

// rden[b][k] = 1 / sum_c part[b][c][k];  grid (8,8), block 256
__global__ void rcp_k(const float* __restrict__ part, float* __restrict__ rden)
{
    const int b = blockIdx.y;
    const int k = blockIdx.x * 256 + threadIdx.x;
    float s = 0.f;
#pragma unroll
    for (int c = 0; c < 16; ++c) s += part[((long)b * 16 + c) * 2048 + k];
    rden[b * 2048 + k] = 1.0f / s;
}

// Vt[b][d][k] = v[b][k][d] * rden[b][k]; grid (64,32,8), block (32,8)
__global__ void vt_k(const u16* __restrict__ qkv, const float* __restrict__ rden,
                     u16* __restrict__ Vt)
{
    __shared__ float t[32][33];
    const int b = blockIdx.z;
    const int k0 = blockIdx.x * 32, d0 = blockIdx.y * 32;
    const int tx = threadIdx.x, ty = threadIdx.y;
#pragma unroll
    for (int j = 0; j < 32; j += 8) {
        const int k = k0 + ty + j;
        t[ty + j][tx] = bf2f(qkv[((long)b * 2048 + k) * 3072 + 2048 + d0 + tx])
                        * rden[b * 2048 + k];
    }
    __syncthreads();
#pragma unroll
    for (int j = 0; j < 32; j += 8)
        Vt[((long)b * 1024 + d0 + ty + j) * 2048 + k0 + tx] = f2bf(t[tx][ty + j]);
}

// ---------------------------------------------------------------------------
extern "C" void kernel_launch(void* const* d_in, const int* in_sizes, int n_in,
                              void* d_out, int out_size, void* d_ws, size_t ws_size,
                              hipStream_t stream)
{
    const float* x  = (const float*)d_in[0];
    const float* Wq = (const float*)d_in[1];
    const float* bq = (const float*)d_in[2];
    const float* Wk = (const float*)d_in[3];
    const float* bk = (const float*)d_in[4];
    const float* Wv = (const float*)d_in[5];
    const float* bv = (const float*)d_in[6];

    char* ws = (char*)d_ws;
    u16*   qkv  = (u16*)(ws);                     // [16384][3072] bf16
    u16*   E    = (u16*)(ws + 100663296);         // [8][2048][2048] bf16
    u16*   Vt   = (u16*)(ws + 167772160);         // [8][1024][2048] bf16
    u16*   xb   = (u16*)(ws + 201326592);         // [16384][1024] bf16
    u16*   Wt   = (u16*)(ws + 234881024);         // [3072][1024] bf16
    float* bcat = (float*)(ws + 241172480);       // [3072] f32
    float* part = (float*)(ws + 241184768);       // [8][16][2048] f32
    float* rden = (float*)(ws + 243281920);       // [8][2048] f32

    const long sQKV = (long)2048 * 3072;
    const long sE   = (long)2048 * 2048;
    const long sVt  = (long)1024 * 2048;
    const long sO   = (long)2048 * 1024;

    cast_x_k<<<8192, 256, 0, stream>>>(x, xb);
    wt_k<<<dim3(32, 32, 3), dim3(32, 8), 0, stream>>>(Wq, Wk, Wv, Wt);
    bias_k<<<12, 256, 0, stream>>>(bq, bk, bv, bcat);
    // qkv = x @ Wt^T + bias   (M=16384, N=3072, K=1024)
    gemm256<0><<<dim3(64, 12, 1), 512, 0, stream>>>(
        xb, 1024, 0, Wt, 1024, 0, qkv, 3072, 0, bcat, nullptr, 0.f, 1024);
    // E = exp(scale * Q @ K^T), fused column-sum partials (M=N=2048, K=1024)
    gemm256<1><<<dim3(8, 8, 8), 512, 0, stream>>>(
        qkv, 3072, sQKV, qkv + 1024, 3072, sQKV, E, 2048, sE,
        nullptr, part, 0.03125f, 1024);
    rcp_k<<<dim3(8, 8), 256, 0, stream>>>(part, rden);
    vt_k<<<dim3(64, 32, 8), dim3(32, 8), 0, stream>>>(qkv, rden, Vt);
    // out = E @ Vt^T  (M=2048, N=1024, K=2048, fp32 out)
    gemm256<2><<<dim3(8, 4, 8), 512, 0, stream>>>(
        E, 2048, sE, Vt, 2048, sVt, d_out, 1024, sO,
        nullptr, nullptr, 1.f, 2048);
}